// Round 1
// baseline (207.635 us; speedup 1.0000x reference)
//
#include <hip/hip_runtime.h>
#include <math.h>

#define Bz 32
#define Sz 4096
#define Hz 32
#define Gz 2
#define Dz 128
#define HIDz 4096
#define QKVz 4608
#define SC 256
#define NCH 16
#define TS 64

static __device__ __forceinline__ void fma4(float4& a, float s, const float4& v) {
  a.x = fmaf(s, v.x, a.x);
  a.y = fmaf(s, v.y, a.y);
  a.z = fmaf(s, v.z, a.z);
  a.w = fmaf(s, v.w, a.w);
}

// ---------------- split-K GEMM partial: part[kt][b][j] = sum_{k in chunk} X[b][k]*W[k][j]
// grid (N/256, KT), block 256. Thread: 4 j-cols x 8 b-rows.
__global__ __launch_bounds__(256) void gemm_partial(
    const float* __restrict__ X, const float* __restrict__ W,
    float* __restrict__ part, int K, int N, int KH) {
  extern __shared__ float hl[];  // [32][KH+4]
  const int stride = KH + 4;
  const int t = threadIdx.x;
  const int k0 = blockIdx.y * KH;
  const int cols4 = KH >> 2;
  const int total4 = Bz * cols4;
  for (int fi = t; fi < total4; fi += 256) {
    const int row = fi / cols4;
    const int c4 = fi - row * cols4;
    const float4 v = *(const float4*)&X[(size_t)row * K + k0 + c4 * 4];
    *(float4*)&hl[row * stride + c4 * 4] = v;
  }
  __syncthreads();
  const int jl = t & 63;
  const int b0 = (t >> 6) * 8;
  const int j = blockIdx.x * 256 + jl * 4;
  float4 acc[8];
  #pragma unroll
  for (int i = 0; i < 8; i++) acc[i] = make_float4(0.f, 0.f, 0.f, 0.f);
  for (int kk = 0; kk < KH; kk += 4) {
    const float4 w0 = *(const float4*)&W[(size_t)(k0 + kk + 0) * N + j];
    const float4 w1 = *(const float4*)&W[(size_t)(k0 + kk + 1) * N + j];
    const float4 w2 = *(const float4*)&W[(size_t)(k0 + kk + 2) * N + j];
    const float4 w3 = *(const float4*)&W[(size_t)(k0 + kk + 3) * N + j];
    #pragma unroll
    for (int bi = 0; bi < 8; bi++) {
      const float4 hb = *(const float4*)&hl[(b0 + bi) * stride + kk];
      fma4(acc[bi], hb.x, w0);
      fma4(acc[bi], hb.y, w1);
      fma4(acc[bi], hb.z, w2);
      fma4(acc[bi], hb.w, w3);
    }
  }
  #pragma unroll
  for (int bi = 0; bi < 8; bi++) {
    *(float4*)&part[((size_t)blockIdx.y * Bz + b0 + bi) * N + j] = acc[bi];
  }
}

// ---------------- reduce QKV partials + bias, apply RoPE, emit q_rot (scaled), k_rot, v_new
// grid (32, 9), block 256 = 4 heads x 64 d-pairs
__global__ __launch_bounds__(256) void qkv_finish(
    const float* __restrict__ part, const float* __restrict__ bias,
    const int* __restrict__ positions, int KT,
    float* __restrict__ qrot, float* __restrict__ krot, float* __restrict__ vnew) {
  const int t = threadIdx.x;
  const int b = blockIdx.x;
  const int head = blockIdx.y * 4 + (t >> 6);
  const int tp = t & 63;
  const int j0 = head * Dz + tp * 2;
  float s0 = bias[j0];
  float s1 = bias[j0 + 1];
  for (int kt = 0; kt < KT; kt++) {
    const float2 p = *(const float2*)&part[((size_t)kt * Bz + b) * QKVz + j0];
    s0 += p.x;
    s1 += p.y;
  }
  float o0 = s0, o1 = s1;
  if (head < Hz + Gz && tp < 32) {
    // inv_freq[i] = 10000^(-i/32), i = tp
    const float invf = exp2f(-(float)tp * (13.287712379549449f / 32.0f));
    const float a = (float)positions[b] * invf;
    float sn, cs;
    sincosf(a, &sn, &cs);
    o0 = s0 * cs - s1 * sn;
    o1 = s1 * cs + s0 * sn;
  }
  if (head < Hz) {
    const float sc = 0.08838834764831845f;  // D^-0.5 folded into q
    float2 o = make_float2(o0 * sc, o1 * sc);
    *(float2*)&qrot[((size_t)b * Hz + head) * Dz + tp * 2] = o;
  } else if (head < Hz + Gz) {
    float2 o = make_float2(o0, o1);
    *(float2*)&krot[((size_t)b * Gz + (head - Hz)) * Dz + tp * 2] = o;
  } else {
    float2 o = make_float2(s0, s1);
    *(float2*)&vnew[((size_t)b * Gz + (head - Hz - Gz)) * Dz + tp * 2] = o;
  }
}

// ---------------- flash-decode chunk: per (chunk c, g, b) compute m,l and partial PV for 16 heads
// grid (NCH, G, B), block 256
__global__ __launch_bounds__(256) void attn_chunk(
    const float* __restrict__ qrot, const float* __restrict__ kcache,
    const float* __restrict__ vcache, const float* __restrict__ krot,
    const float* __restrict__ vnew, const int* __restrict__ positions,
    float* __restrict__ mbuf, float* __restrict__ lbuf, float* __restrict__ pacc) {
  __shared__ float kl[TS * Dz];      // 32 KB, XOR-swizzled K/V tile
  __shared__ float ql[16 * Dz];      // 8 KB
  __shared__ float pl[16 * 257];     // logits then probs
  const int c = blockIdx.x, g = blockIdx.y, b = blockIdx.z;
  const int pos = positions[b];
  const int s0 = c * SC;
  if (s0 > pos) return;  // chunk fully beyond valid range; combine skips it
  const int n = min(SC, pos + 1 - s0);
  const int t = threadIdx.x;
  // q tile -> LDS (16 heads of this group, pre-scaled)
  for (int i = t; i < 16 * 32; i += 256) {
    *(float4*)&ql[i * 4] =
        *(const float4*)&qrot[((size_t)b * Hz + g * 16 + (i >> 5)) * Dz + (i & 31) * 4];
  }
  const int ntile = (n + TS - 1) / TS;
  // ---- phase 1: logits
  const int sl = t & 63;       // s within tile
  const int hq = t >> 6;       // head quad
  for (int tile = 0; tile < ntile; tile++) {
    __syncthreads();
    const int st = tile * TS;
    for (int si = t; si < TS * 32; si += 256) {
      const int r = si >> 5, c4 = si & 31;
      const int sg = s0 + st + r;  // always < Sz
      const float* src = (sg == pos)
          ? &krot[((size_t)b * Gz + g) * Dz + c4 * 4]
          : &kcache[(((size_t)b * Sz + sg) * Gz + g) * Dz + c4 * 4];
      *(float4*)&kl[(r * 32 + (c4 ^ (r & 7))) * 4] = *(const float4*)src;
    }
    __syncthreads();
    float a0 = 0.f, a1 = 0.f, a2 = 0.f, a3 = 0.f;
    for (int d4 = 0; d4 < 32; d4++) {
      const float4 k4 = *(const float4*)&kl[(sl * 32 + (d4 ^ (sl & 7))) * 4];
      const float4 q0 = *(const float4*)&ql[(hq * 4 + 0) * Dz + d4 * 4];
      const float4 q1 = *(const float4*)&ql[(hq * 4 + 1) * Dz + d4 * 4];
      const float4 q2 = *(const float4*)&ql[(hq * 4 + 2) * Dz + d4 * 4];
      const float4 q3 = *(const float4*)&ql[(hq * 4 + 3) * Dz + d4 * 4];
      a0 += k4.x * q0.x + k4.y * q0.y + k4.z * q0.z + k4.w * q0.w;
      a1 += k4.x * q1.x + k4.y * q1.y + k4.z * q1.z + k4.w * q1.w;
      a2 += k4.x * q2.x + k4.y * q2.y + k4.z * q2.z + k4.w * q2.w;
      a3 += k4.x * q3.x + k4.y * q3.y + k4.z * q3.z + k4.w * q3.w;
    }
    const int srow = st + sl;
    const bool valid = srow < n;
    pl[(hq * 4 + 0) * 257 + srow] = valid ? a0 : -1e30f;
    pl[(hq * 4 + 1) * 257 + srow] = valid ? a1 : -1e30f;
    pl[(hq * 4 + 2) * 257 + srow] = valid ? a2 : -1e30f;
    pl[(hq * 4 + 3) * 257 + srow] = valid ? a3 : -1e30f;
  }
  __syncthreads();
  // ---- phase 2: softmax over chunk (16 lanes per head)
  {
    const int h = t >> 4, l16 = t & 15;
    float m = -1e30f;
    for (int k = 0; k < 16; k++) {
      const int s = l16 + k * 16;
      const float x = (s < n) ? pl[h * 257 + s] : -1e30f;
      m = fmaxf(m, x);
    }
    m = fmaxf(m, __shfl_xor(m, 8, 64));
    m = fmaxf(m, __shfl_xor(m, 4, 64));
    m = fmaxf(m, __shfl_xor(m, 2, 64));
    m = fmaxf(m, __shfl_xor(m, 1, 64));
    float l = 0.f;
    for (int k = 0; k < 16; k++) {
      const int s = l16 + k * 16;
      const float p = (s < n) ? __expf(pl[h * 257 + s] - m) : 0.f;
      pl[h * 257 + s] = p;
      l += p;
    }
    l += __shfl_xor(l, 8, 64);
    l += __shfl_xor(l, 4, 64);
    l += __shfl_xor(l, 2, 64);
    l += __shfl_xor(l, 1, 64);
    if (l16 == 0) {
      const size_t idx = (((size_t)b * Gz + g) * NCH + c) * 16 + h;
      mbuf[idx] = m;
      lbuf[idx] = l;
    }
  }
  // ---- phase 3: PV partial
  const int dg = t & 31;       // d quad
  const int hp = t >> 5;       // head pair
  float4 A0 = make_float4(0.f, 0.f, 0.f, 0.f);
  float4 A1 = make_float4(0.f, 0.f, 0.f, 0.f);
  const int h0 = hp * 2, h1 = hp * 2 + 1;
  for (int tile = 0; tile < ntile; tile++) {
    __syncthreads();
    const int st = tile * TS;
    for (int si = t; si < TS * 32; si += 256) {
      const int r = si >> 5, c4 = si & 31;
      const int sg = s0 + st + r;
      const float* src = (sg == pos)
          ? &vnew[((size_t)b * Gz + g) * Dz + c4 * 4]
          : &vcache[(((size_t)b * Sz + sg) * Gz + g) * Dz + c4 * 4];
      *(float4*)&kl[(r * 32 + (c4 ^ (r & 7))) * 4] = *(const float4*)src;
    }
    __syncthreads();
    for (int r = 0; r < TS; r++) {
      const float p0 = pl[h0 * 257 + st + r];
      const float p1 = pl[h1 * 257 + st + r];
      const float4 v4 = *(const float4*)&kl[(r * 32 + (dg ^ (r & 7))) * 4];
      fma4(A0, p0, v4);
      fma4(A1, p1, v4);
    }
  }
  const size_t base = (((size_t)b * Gz + g) * NCH + c) * 2048;
  *(float4*)&pacc[base + (size_t)h0 * Dz + dg * 4] = A0;
  *(float4*)&pacc[base + (size_t)h1 * Dz + dg * 4] = A1;
}

// ---------------- combine chunk partials -> ctx (B, H*D)
// grid (B*G), block 512 = 16 heads x 32 d-quads
__global__ __launch_bounds__(512) void attn_combine(
    const float* __restrict__ mbuf, const float* __restrict__ lbuf,
    const float* __restrict__ pacc, const int* __restrict__ positions,
    float* __restrict__ ctx) {
  const int bg = blockIdx.x;
  const int b = bg >> 1, g = bg & 1;
  const int t = threadIdx.x;
  const int h = t >> 5, dg = t & 31;
  const int nc = positions[b] / SC + 1;
  const size_t mlb = (size_t)bg * NCH * 16 + h;
  float mstar = -1e30f;
  for (int c = 0; c < nc; c++) mstar = fmaxf(mstar, mbuf[mlb + c * 16]);
  float lsum = 0.f;
  float4 A = make_float4(0.f, 0.f, 0.f, 0.f);
  for (int c = 0; c < nc; c++) {
    const float w = __expf(mbuf[mlb + c * 16] - mstar);
    lsum += w * lbuf[mlb + c * 16];
    const float4 p = *(const float4*)&pacc[((size_t)bg * NCH + c) * 2048 + (size_t)h * Dz + dg * 4];
    fma4(A, w, p);
  }
  const float inv = 1.0f / lsum;
  float4 o = make_float4(A.x * inv, A.y * inv, A.z * inv, A.w * inv);
  *(float4*)&ctx[(size_t)b * (Hz * Dz) + (g * 16 + h) * Dz + dg * 4] = o;
}

// ---------------- reduce dense partials -> out
__global__ __launch_bounds__(256) void reduce_out(
    const float* __restrict__ part, float* __restrict__ out, int KT) {
  const int idx = blockIdx.x * 256 + threadIdx.x;  // over 32*4096
  const int b = idx >> 12;
  const int j = idx & 4095;
  float s = 0.f;
  for (int kt = 0; kt < KT; kt++) s += part[((size_t)kt * Bz + b) * HIDz + j];
  out[idx] = s;
}

extern "C" void kernel_launch(void* const* d_in, const int* in_sizes, int n_in,
                              void* d_out, int out_size, void* d_ws, size_t ws_size,
                              hipStream_t stream) {
  const float* hidden = (const float*)d_in[0];
  const int* positions = (const int*)d_in[1];
  const float* kcache = (const float*)d_in[2];
  const float* vcache = (const float*)d_in[3];
  const float* Wqkv = (const float*)d_in[4];
  const float* bqkv = (const float*)d_in[5];
  const float* Wd = (const float*)d_in[6];
  float* out = (float*)d_out;

  // workspace carve (floats). p1 reused for dense partials (QKV partial is larger).
  auto need = [](int KT) -> size_t {
    return (size_t)KT * Bz * QKVz        // p1 (aliased for dense partial too)
         + (size_t)Bz * Hz * Dz          // qrot
         + (size_t)Bz * Gz * Dz * 2      // krot + vnew
         + (size_t)Bz * Gz * NCH * 16 * 2  // mbuf + lbuf
         + (size_t)Bz * Gz * NCH * 2048  // pacc
         + (size_t)Bz * HIDz;            // ctx
  };
  int KT = 32;
  if (need(32) * sizeof(float) > ws_size) KT = 16;
  const int KH = HIDz / KT;

  float* w = (float*)d_ws;
  float* p1 = w;    w += (size_t)KT * Bz * QKVz;
  float* qrot = w;  w += (size_t)Bz * Hz * Dz;
  float* krot = w;  w += (size_t)Bz * Gz * Dz;
  float* vnew = w;  w += (size_t)Bz * Gz * Dz;
  float* mbuf = w;  w += (size_t)Bz * Gz * NCH * 16;
  float* lbuf = w;  w += (size_t)Bz * Gz * NCH * 16;
  float* pacc = w;  w += (size_t)Bz * Gz * NCH * 2048;
  float* ctx = w;

  const size_t smem = (size_t)Bz * (KH + 4) * sizeof(float);

  gemm_partial<<<dim3(QKVz / 256, KT), 256, smem, stream>>>(hidden, Wqkv, p1, HIDz, QKVz, KH);
  qkv_finish<<<dim3(Bz, 9), 256, 0, stream>>>(p1, bqkv, positions, KT, qrot, krot, vnew);
  attn_chunk<<<dim3(NCH, Gz, Bz), 256, 0, stream>>>(qrot, kcache, vcache, krot, vnew, positions,
                                                    mbuf, lbuf, pacc);
  attn_combine<<<dim3(Bz * Gz), 512, 0, stream>>>(mbuf, lbuf, pacc, positions, ctx);
  gemm_partial<<<dim3(HIDz / 256, KT), 256, smem, stream>>>(ctx, Wd, p1, Hz * Dz, HIDz, KH);
  reduce_out<<<dim3(Bz * HIDz / 256), 256, 0, stream>>>(p1, out, KT);
}